// Round 4
// baseline (270.142 us; speedup 1.0000x reference)
//
#include <hip/hip_runtime.h>
#include <hip/hip_bf16.h>
#include <math.h>

#define NH 12
#define HD 64
#define NSEQ 1024
#define DMODEL 768
#define LOG2E 1.44269504f

typedef unsigned short ushort_t;
typedef float f32x4 __attribute__((ext_vector_type(4)));
typedef short bf16x8 __attribute__((ext_vector_type(8)));

__device__ __forceinline__ ushort_t f2bf(float f) {
    unsigned int u = __float_as_uint(f);
    u += 0x7FFFu + ((u >> 16) & 1u);   // RNE
    return (ushort_t)(u >> 16);
}

__device__ __forceinline__ unsigned pk2(float x, float y) {
    __hip_bfloat162 t = __float22bfloat162_rn(make_float2(x, y));
    union { __hip_bfloat162 b; unsigned u; } c; c.b = t;
    return c.u;
}

__device__ __forceinline__ uint4 cvt8(float4 a, float4 b) {
    uint4 r;
    r.x = pk2(a.x, a.y); r.y = pk2(a.z, a.w);
    r.z = pk2(b.x, b.y); r.w = pk2(b.z, b.w);
    return r;
}

// ---------------------------------------------------------------------------
// bias_pre: per (b,i,j) pack = (bf16(elev_bias*log2e) << 16) | bucket_idx
// ---------------------------------------------------------------------------
__device__ __forceinline__ int bucketf(int rel) {
    const int n = -rel;
    const int u = (n < 0) ? 16 : 0;
    const int a = n < 0 ? -n : n;
    if (a < 8) return u + a;
    int v = 8 + (int)(log2f((float)a * 0.125f) * 2.0f + 1e-4f);
    if (v > 15) v = 15;
    return u + v;
}

__global__ __launch_bounds__(256) void bias_pre(
    const float* __restrict__ coords, const float* __restrict__ elev,
    const float* __restrict__ alpha_p, unsigned* __restrict__ pack)
{
    const int blk = blockIdx.x;
    const int b = blk >> 10, i = blk & 1023;
    const int t = threadIdx.x;
    const float alpha = alpha_p[0];
    const float2 ci = *(const float2*)&coords[(size_t)(b * NSEQ + i) * 2];
    const int cxi = (int)(ci.x * 128.0f), cyi = (int)(ci.y * 128.0f);
    const float ei = elev[b * NSEQ + i];
    const int j0 = t * 4;
    const float4 c01 = *(const float4*)&coords[(size_t)(b * NSEQ + j0) * 2];
    const float4 c23 = *(const float4*)&coords[(size_t)(b * NSEQ + j0 + 2) * 2];
    const float4 ej4 = *(const float4*)&elev[b * NSEQ + j0];
    const float cjx[4] = {c01.x, c01.z, c23.x, c23.z};
    const float cjy[4] = {c01.y, c01.w, c23.y, c23.w};
    const float ejv[4] = {ej4.x, ej4.y, ej4.z, ej4.w};
    unsigned r[4];
    #pragma unroll
    for (int k = 0; k < 4; ++k) {
        const int bx = bucketf(cxi - (int)(cjx[k] * 128.0f));
        const int by = bucketf(cyi - (int)(cjy[k] * 128.0f));
        const int idx = (bx << 5) + by;
        const float ed = (ejv[k] - ei) * 1e-3f;
        const float eb = fmaxf(-alpha * fmaxf(ed, 0.0f), -10.0f) * LOG2E;
        r[k] = ((unsigned)f2bf(eb) << 16) | (unsigned)idx;
    }
    uint4 o; o.x = r[0]; o.y = r[1]; o.z = r[2]; o.w = r[3];
    *(uint4*)&pack[((size_t)b << 20) + (size_t)i * NSEQ + j0] = o;
}

// ---------------------------------------------------------------------------
// QKV GEMM (bf16 MFMA, fp32 inputs converted in staging).
// 128x128 tile, 256 thr, BK=32. Q pre-scaled by 0.125*log2e.
// ---------------------------------------------------------------------------
__global__ __launch_bounds__(256) void qkv_gemm(
    const float* __restrict__ A, const float* __restrict__ B,
    const float* __restrict__ bias,
    ushort_t* __restrict__ Qb, ushort_t* __restrict__ Kb, ushort_t* __restrict__ Vtb)
{
    __shared__ __align__(16) ushort_t As[128 * 40];
    __shared__ __align__(16) ushort_t Bs[128 * 40];
    const int t = threadIdx.x;
    const int lane = t & 63, w = t >> 6;
    const int wr = w >> 1, wc = w & 1;
    const int col = lane & 15, quad = lane >> 4;
    const int m0 = blockIdx.y * 128, c0 = blockIdx.x * 128;

    const f32x4 zero = {0.f, 0.f, 0.f, 0.f};
    f32x4 acc[4][4];
    #pragma unroll
    for (int i = 0; i < 4; ++i)
        #pragma unroll
        for (int j = 0; j < 4; ++j) acc[i][j] = zero;

    const int row_s = t >> 2, cq = (t & 3) * 8;
    for (int k0 = 0; k0 < DMODEL; k0 += 32) {
        const float* a0p = &A[(size_t)(m0 + row_s) * DMODEL + k0 + cq];
        const float* a1p = &A[(size_t)(m0 + 64 + row_s) * DMODEL + k0 + cq];
        const float* b0p = &B[(size_t)(c0 + row_s) * DMODEL + k0 + cq];
        const float* b1p = &B[(size_t)(c0 + 64 + row_s) * DMODEL + k0 + cq];
        const uint4 a0 = cvt8(*(const float4*)a0p, *(const float4*)(a0p + 4));
        const uint4 a1 = cvt8(*(const float4*)a1p, *(const float4*)(a1p + 4));
        const uint4 b0 = cvt8(*(const float4*)b0p, *(const float4*)(b0p + 4));
        const uint4 b1 = cvt8(*(const float4*)b1p, *(const float4*)(b1p + 4));
        __syncthreads();
        *(uint4*)&As[row_s * 40 + cq] = a0;
        *(uint4*)&As[(64 + row_s) * 40 + cq] = a1;
        *(uint4*)&Bs[row_s * 40 + cq] = b0;
        *(uint4*)&Bs[(64 + row_s) * 40 + cq] = b1;
        __syncthreads();
        bf16x8 af[4], bf[4];
        #pragma unroll
        for (int im = 0; im < 4; ++im)
            af[im] = *(const bf16x8*)&As[(wr * 64 + im * 16 + col) * 40 + quad * 8];
        #pragma unroll
        for (int jn = 0; jn < 4; ++jn)
            bf[jn] = *(const bf16x8*)&Bs[(wc * 64 + jn * 16 + col) * 40 + quad * 8];
        #pragma unroll
        for (int im = 0; im < 4; ++im)
            #pragma unroll
            for (int jn = 0; jn < 4; ++jn)
                acc[im][jn] = __builtin_amdgcn_mfma_f32_16x16x32_bf16(af[im], bf[jn], acc[im][jn], 0, 0, 0);
    }

    const int cb = c0 + wc * 64;
    const int s = cb / DMODEL;
    const int h = (cb % DMODEL) >> 6;
    const int b = m0 >> 10;
    const int bh = b * NH + h;
    const int n0 = (m0 & (NSEQ - 1)) + wr * 64;
    const float qsc = 0.125f * LOG2E;

    #pragma unroll
    for (int im = 0; im < 4; ++im) {
        #pragma unroll
        for (int jn = 0; jn < 4; ++jn) {
            const int d = jn * 16 + col;
            const float bv = bias[cb + d];
            const f32x4 a = acc[im][jn];
            if (s == 0) {
                #pragma unroll
                for (int r = 0; r < 4; ++r) {
                    const int n = n0 + im * 16 + quad * 4 + r;
                    Qb[((size_t)bh * NSEQ + n) * HD + d] = f2bf((a[r] + bv) * qsc);
                }
            } else if (s == 1) {
                #pragma unroll
                for (int r = 0; r < 4; ++r) {
                    const int n = n0 + im * 16 + quad * 4 + r;
                    Kb[((size_t)bh * NSEQ + n) * HD + d] = f2bf(a[r] + bv);
                }
            } else {
                uint2 p;
                p.x = pk2(a[0] + bv, a[1] + bv);
                p.y = pk2(a[2] + bv, a[3] + bv);
                *(uint2*)&Vtb[((size_t)bh * HD + d) * NSEQ + n0 + im * 16 + quad * 4] = p;
            }
        }
    }
}

// ---------------------------------------------------------------------------
// Fused flash attention, barrier-free main loop.
// All K/V/Q MFMA fragments loaded directly from global (LLC-resident).
// P round-trips through wave-private LDS rows (in-order DS, no barrier).
// exp2 domain; l-reduction deferred to epilogue.
// ---------------------------------------------------------------------------
__global__ __launch_bounds__(256) void attn_mfma(
    const ushort_t* __restrict__ Qb, const ushort_t* __restrict__ Kb,
    const ushort_t* __restrict__ Vtb,
    const unsigned* __restrict__ pack,
    const float* __restrict__ table,
    ushort_t* __restrict__ Ob)
{
    __shared__ __align__(16) ushort_t Ps[64 * 72];
    __shared__ float tab[1024];
    __shared__ float red[4];

    const int t = threadIdx.x;
    const int lane = t & 63, w = t >> 6;
    const int col = lane & 15, quad = lane >> 4;
    const int bid = blockIdx.x;
    const int it = bid & 15, bh = bid >> 4;
    const int h = bh % NH, b = bh / NH;
    const int i0 = it * 64;

    // per-head table column (log2e-scaled) + block max
    float lm = -1e30f;
    for (int i = t; i < 1024; i += 256) {
        const float v = table[i * NH + h] * LOG2E;
        tab[i] = v;
        lm = fmaxf(lm, v);
    }
    #pragma unroll
    for (int off = 1; off < 64; off <<= 1)
        lm = fmaxf(lm, __shfl_xor(lm, off));
    if (lane == 0) red[w] = lm;

    // Q fragments direct from global (wave-private rows i0+w*16 .. +15)
    const ushort_t* Qg = Qb + ((size_t)bh * NSEQ + i0 + w * 16 + col) * HD;
    const bf16x8 aq0 = *(const bf16x8*)(Qg + quad * 8);
    const bf16x8 aq1 = *(const bf16x8*)(Qg + 32 + quad * 8);

    __syncthreads();   // tab + red published; ONLY barrier in the kernel
    const float maxrb = fmaxf(fmaxf(red[0], red[1]), fmaxf(red[2], red[3]));

    const f32x4 zero = {0.f, 0.f, 0.f, 0.f};
    f32x4 o_acc[4];
    #pragma unroll
    for (int i = 0; i < 4; ++i) o_acc[i] = zero;
    float m_r[4] = {-1e30f, -1e30f, -1e30f, -1e30f};
    float l_r[4] = {0.f, 0.f, 0.f, 0.f};

    const size_t kvbase = (size_t)bh * NSEQ * HD;
    const int rowb = w * 16 + quad * 4;
    const unsigned* prow = pack + ((size_t)b << 20) + (size_t)(i0 + rowb) * NSEQ + col;
    // lane-base pointers for direct fragment loads
    const ushort_t* Kl = Kb + kvbase + (size_t)col * HD + quad * 8;       // + (j0+jb*16)*HD (+32)
    const ushort_t* Vl = Vtb + kvbase + (size_t)col * NSEQ + quad * 8;    // + db*16*NSEQ + j0 (+32)

    for (int jt = 0; jt < 16; ++jt) {
        const int j0 = jt * 64;

        // issue all of this tile's loads up front (K for S, pk for softmax, V for PV)
        bf16x8 kf[8], vf[8];
        #pragma unroll
        for (int jb = 0; jb < 4; ++jb) {
            kf[jb * 2 + 0] = *(const bf16x8*)(Kl + (size_t)(j0 + jb * 16) * HD);
            kf[jb * 2 + 1] = *(const bf16x8*)(Kl + (size_t)(j0 + jb * 16) * HD + 32);
        }
        unsigned pkr[16];
        #pragma unroll
        for (int r = 0; r < 4; ++r)
            #pragma unroll
            for (int jb = 0; jb < 4; ++jb)
                pkr[r * 4 + jb] = prow[(size_t)r * NSEQ + j0 + jb * 16];
        #pragma unroll
        for (int db = 0; db < 4; ++db) {
            vf[db * 2 + 0] = *(const bf16x8*)(Vl + (size_t)(db * 16) * NSEQ + j0);
            vf[db * 2 + 1] = *(const bf16x8*)(Vl + (size_t)(db * 16) * NSEQ + j0 + 32);
        }

        // S = Q K^T  (log2 domain)
        f32x4 sacc[4];
        #pragma unroll
        for (int jb = 0; jb < 4; ++jb) {
            sacc[jb] = zero;
            sacc[jb] = __builtin_amdgcn_mfma_f32_16x16x32_bf16(aq0, kf[jb * 2 + 0], sacc[jb], 0, 0, 0);
            sacc[jb] = __builtin_amdgcn_mfma_f32_16x16x32_bf16(aq1, kf[jb * 2 + 1], sacc[jb], 0, 0, 0);
        }

        // online softmax (exp2); P -> wave-private LDS rows
        #pragma unroll
        for (int r = 0; r < 4; ++r) {
            const int ri = rowb + r;
            float rmax = fmaxf(fmaxf(sacc[0][r], sacc[1][r]),
                               fmaxf(sacc[2][r], sacc[3][r]));
            #pragma unroll
            for (int off = 1; off < 16; off <<= 1)
                rmax = fmaxf(rmax, __shfl_xor(rmax, off));
            const float m_new = fmaxf(m_r[r], rmax + maxrb);
            const float corr = exp2f(m_r[r] - m_new);
            m_r[r] = m_new;
            float p[4];
            #pragma unroll
            for (int jb = 0; jb < 4; ++jb) {
                const unsigned pkv = pkr[r * 4 + jb];
                const float ebf = __uint_as_float(pkv & 0xFFFF0000u);
                const float rb = tab[pkv & 1023u];
                p[jb] = exp2f(sacc[jb][r] + rb + ebf - m_new);
            }
            l_r[r] = l_r[r] * corr + ((p[0] + p[1]) + (p[2] + p[3]));
            const unsigned u01 = pk2(p[0], p[1]);
            const unsigned u23 = pk2(p[2], p[3]);
            Ps[ri * 72 + col]      = (ushort_t)u01;
            Ps[ri * 72 + 16 + col] = (ushort_t)(u01 >> 16);
            Ps[ri * 72 + 32 + col] = (ushort_t)u23;
            Ps[ri * 72 + 48 + col] = (ushort_t)(u23 >> 16);
            #pragma unroll
            for (int db = 0; db < 4; ++db) o_acc[db][r] *= corr;
        }

        // O += P V  (P read back from wave-private rows; same-wave DS is in-order)
        const bf16x8 ap0 = *(const bf16x8*)&Ps[(w * 16 + col) * 72 + quad * 8];
        const bf16x8 ap1 = *(const bf16x8*)&Ps[(w * 16 + col) * 72 + 32 + quad * 8];
        #pragma unroll
        for (int db = 0; db < 4; ++db) {
            o_acc[db] = __builtin_amdgcn_mfma_f32_16x16x32_bf16(ap0, vf[db * 2 + 0], o_acc[db], 0, 0, 0);
            o_acc[db] = __builtin_amdgcn_mfma_f32_16x16x32_bf16(ap1, vf[db * 2 + 1], o_acc[db], 0, 0, 0);
        }
    }

    // epilogue: finish deferred l reduction, normalize, store bf16
    #pragma unroll
    for (int r = 0; r < 4; ++r) {
        float l = l_r[r];
        #pragma unroll
        for (int off = 1; off < 16; off <<= 1)
            l += __shfl_xor(l, off);
        const float inv = 1.f / l;
        const int ri = rowb + r;
        const size_t base = ((size_t)(b * NSEQ) + i0 + ri) * DMODEL + h * HD;
        #pragma unroll
        for (int db = 0; db < 4; ++db)
            Ob[base + db * 16 + col] = f2bf(o_acc[db][r] * inv);
    }
}

// ---------------------------------------------------------------------------
// Proj GEMM (bf16 MFMA): A bf16, B fp32 converted in staging; fp32 out
// ---------------------------------------------------------------------------
__global__ __launch_bounds__(256) void proj_gemm(
    const ushort_t* __restrict__ A, const float* __restrict__ B,
    const float* __restrict__ bias, float* __restrict__ out)
{
    __shared__ __align__(16) ushort_t As[128 * 40];
    __shared__ __align__(16) ushort_t Bs[128 * 40];
    const int t = threadIdx.x;
    const int lane = t & 63, w = t >> 6;
    const int wr = w >> 1, wc = w & 1;
    const int col = lane & 15, quad = lane >> 4;
    const int m0 = blockIdx.y * 128, c0 = blockIdx.x * 128;

    const f32x4 zero = {0.f, 0.f, 0.f, 0.f};
    f32x4 acc[4][4];
    #pragma unroll
    for (int i = 0; i < 4; ++i)
        #pragma unroll
        for (int j = 0; j < 4; ++j) acc[i][j] = zero;

    const int row_s = t >> 2, cq = (t & 3) * 8;
    for (int k0 = 0; k0 < DMODEL; k0 += 32) {
        const uint4 a0 = *(const uint4*)&A[(size_t)(m0 + row_s) * DMODEL + k0 + cq];
        const uint4 a1 = *(const uint4*)&A[(size_t)(m0 + 64 + row_s) * DMODEL + k0 + cq];
        const float* b0p = &B[(size_t)(c0 + row_s) * DMODEL + k0 + cq];
        const float* b1p = &B[(size_t)(c0 + 64 + row_s) * DMODEL + k0 + cq];
        const uint4 b0 = cvt8(*(const float4*)b0p, *(const float4*)(b0p + 4));
        const uint4 b1 = cvt8(*(const float4*)b1p, *(const float4*)(b1p + 4));
        __syncthreads();
        *(uint4*)&As[row_s * 40 + cq] = a0;
        *(uint4*)&As[(64 + row_s) * 40 + cq] = a1;
        *(uint4*)&Bs[row_s * 40 + cq] = b0;
        *(uint4*)&Bs[(64 + row_s) * 40 + cq] = b1;
        __syncthreads();
        bf16x8 af[4], bf[4];
        #pragma unroll
        for (int im = 0; im < 4; ++im)
            af[im] = *(const bf16x8*)&As[(wr * 64 + im * 16 + col) * 40 + quad * 8];
        #pragma unroll
        for (int jn = 0; jn < 4; ++jn)
            bf[jn] = *(const bf16x8*)&Bs[(wc * 64 + jn * 16 + col) * 40 + quad * 8];
        #pragma unroll
        for (int im = 0; im < 4; ++im)
            #pragma unroll
            for (int jn = 0; jn < 4; ++jn)
                acc[im][jn] = __builtin_amdgcn_mfma_f32_16x16x32_bf16(af[im], bf[jn], acc[im][jn], 0, 0, 0);
    }

    #pragma unroll
    for (int im = 0; im < 4; ++im) {
        #pragma unroll
        for (int jn = 0; jn < 4; ++jn) {
            const int c = c0 + wc * 64 + jn * 16 + col;
            const float bv = bias[c];
            #pragma unroll
            for (int r = 0; r < 4; ++r) {
                const int m = m0 + wr * 64 + im * 16 + quad * 4 + r;
                out[(size_t)m * DMODEL + c] = acc[im][jn][r] + bv;
            }
        }
    }
}

extern "C" void kernel_launch(void* const* d_in, const int* in_sizes, int n_in,
                              void* d_out, int out_size, void* d_ws, size_t ws_size,
                              hipStream_t stream) {
    const float* x       = (const float*)d_in[0];
    const float* coords  = (const float*)d_in[1];
    const float* elev    = (const float*)d_in[2];
    const float* qkv_w   = (const float*)d_in[3];
    const float* qkv_b   = (const float*)d_in[4];
    const float* proj_w  = (const float*)d_in[5];
    const float* proj_b  = (const float*)d_in[6];
    const float* btable  = (const float*)d_in[7];
    const float* alpha   = (const float*)d_in[8];
    float* out = (float*)d_out;

    ushort_t* wsu = (ushort_t*)d_ws;
    ushort_t* Qb  = wsu;
    ushort_t* Kb  = wsu + 3145728;
    ushort_t* Vtb = wsu + 6291456;
    ushort_t* Ob  = wsu + 9437184;
    unsigned* pck = (unsigned*)(wsu + 12582912);   // 4M uint32 = 16 MB

    bias_pre<<<4096, 256, 0, stream>>>(coords, elev, alpha, pck);
    qkv_gemm<<<dim3(18, 32), 256, 0, stream>>>(x, qkv_w, qkv_b, Qb, Kb, Vtb);
    attn_mfma<<<768, 256, 0, stream>>>(Qb, Kb, Vtb, pck, btable, Ob);
    proj_gemm<<<dim3(6, 32), 256, 0, stream>>>(Ob, proj_w, proj_b, out);
}

// Round 6
// 206.968 us; speedup vs baseline: 1.3052x; 1.3052x over previous
//
#include <hip/hip_runtime.h>
#include <hip/hip_bf16.h>
#include <math.h>

#define NH 12
#define HD 64
#define NSEQ 1024
#define DMODEL 768
#define LOG2E 1.44269504f

typedef unsigned short ushort_t;
typedef float f32x4 __attribute__((ext_vector_type(4)));
typedef short bf16x8 __attribute__((ext_vector_type(8)));

__device__ __forceinline__ ushort_t f2bf(float f) {
    unsigned int u = __float_as_uint(f);
    u += 0x7FFFu + ((u >> 16) & 1u);   // RNE
    return (ushort_t)(u >> 16);
}

__device__ __forceinline__ unsigned pk2(float x, float y) {
    __hip_bfloat162 t = __float22bfloat162_rn(make_float2(x, y));
    union { __hip_bfloat162 b; unsigned u; } c; c.b = t;
    return c.u;
}

// ---------------------------------------------------------------------------
// fp32 -> bf16 conversion of x, qkv_w, proj_w
// ---------------------------------------------------------------------------
#define XB_N   3145728u
#define WQB_N  1769472u
#define PWB_N  589824u

__global__ __launch_bounds__(256) void convert_kernel(
    const float* __restrict__ x, const float* __restrict__ w1,
    const float* __restrict__ w2, ushort_t* __restrict__ dst)
{
    const unsigned i = blockIdx.x * 256 + threadIdx.x;      // 8-elem chunk id
    const unsigned n0 = XB_N / 8, n1 = n0 + WQB_N / 8, n2 = n1 + PWB_N / 8;
    if (i >= n2) return;
    const float* src; unsigned off;
    if (i < n0)      { src = x;  off = i; }
    else if (i < n1) { src = w1; off = i - n0; }
    else             { src = w2; off = i - n1; }
    const float4 a = ((const float4*)src)[off * 2];
    const float4 b = ((const float4*)src)[off * 2 + 1];
    uint4 pk;
    pk.x = pk2(a.x, a.y); pk.y = pk2(a.z, a.w);
    pk.z = pk2(b.x, b.y); pk.w = pk2(b.z, b.w);
    ((uint4*)dst)[i] = pk;
}

// ---------------------------------------------------------------------------
// bias_pre: per (b,i,j) pack = (bf16(elev_bias*log2e) << 16) | bucket_idx
// ---------------------------------------------------------------------------
__device__ __forceinline__ int bucketf(int rel) {
    const int n = -rel;
    const int u = (n < 0) ? 16 : 0;
    const int a = n < 0 ? -n : n;
    if (a < 8) return u + a;
    int v = 8 + (int)(log2f((float)a * 0.125f) * 2.0f + 1e-4f);
    if (v > 15) v = 15;
    return u + v;
}

__global__ __launch_bounds__(256) void bias_pre(
    const float* __restrict__ coords, const float* __restrict__ elev,
    const float* __restrict__ alpha_p, unsigned* __restrict__ pack)
{
    const int blk = blockIdx.x;
    const int b = blk >> 10, i = blk & 1023;
    const int t = threadIdx.x;
    const float alpha = alpha_p[0];
    const float2 ci = *(const float2*)&coords[(size_t)(b * NSEQ + i) * 2];
    const int cxi = (int)(ci.x * 128.0f), cyi = (int)(ci.y * 128.0f);
    const float ei = elev[b * NSEQ + i];
    const int j0 = t * 4;
    const float4 c01 = *(const float4*)&coords[(size_t)(b * NSEQ + j0) * 2];
    const float4 c23 = *(const float4*)&coords[(size_t)(b * NSEQ + j0 + 2) * 2];
    const float4 ej4 = *(const float4*)&elev[b * NSEQ + j0];
    const float cjx[4] = {c01.x, c01.z, c23.x, c23.z};
    const float cjy[4] = {c01.y, c01.w, c23.y, c23.w};
    const float ejv[4] = {ej4.x, ej4.y, ej4.z, ej4.w};
    unsigned r[4];
    #pragma unroll
    for (int k = 0; k < 4; ++k) {
        const int bx = bucketf(cxi - (int)(cjx[k] * 128.0f));
        const int by = bucketf(cyi - (int)(cjy[k] * 128.0f));
        const int idx = (bx << 5) + by;
        const float ed = (ejv[k] - ei) * 1e-3f;
        const float eb = fmaxf(-alpha * fmaxf(ed, 0.0f), -10.0f) * LOG2E;
        r[k] = ((unsigned)f2bf(eb) << 16) | (unsigned)idx;
    }
    uint4 o; o.x = r[0]; o.y = r[1]; o.z = r[2]; o.w = r[3];
    *(uint4*)&pack[((size_t)b << 20) + (size_t)i * NSEQ + j0] = o;
}

// ---------------------------------------------------------------------------
// QKV GEMM (bf16 MFMA): 128x128 tile, 256 thr, BK=32.
// Q pre-scaled by 0.125*log2e; V transposed [bh][d][n].
// ---------------------------------------------------------------------------
__global__ __launch_bounds__(256) void qkv_gemm(
    const ushort_t* __restrict__ A, const ushort_t* __restrict__ B,
    const float* __restrict__ bias,
    ushort_t* __restrict__ Qb, ushort_t* __restrict__ Kb, ushort_t* __restrict__ Vtb)
{
    __shared__ __align__(16) ushort_t As[128 * 40];
    __shared__ __align__(16) ushort_t Bs[128 * 40];
    const int t = threadIdx.x;
    const int lane = t & 63, w = t >> 6;
    const int wr = w >> 1, wc = w & 1;
    const int col = lane & 15, quad = lane >> 4;
    const int m0 = blockIdx.y * 128, c0 = blockIdx.x * 128;

    const f32x4 zero = {0.f, 0.f, 0.f, 0.f};
    f32x4 acc[4][4];
    #pragma unroll
    for (int i = 0; i < 4; ++i)
        #pragma unroll
        for (int j = 0; j < 4; ++j) acc[i][j] = zero;

    const int row_s = t >> 2, cq = (t & 3) * 8;
    for (int k0 = 0; k0 < DMODEL; k0 += 32) {
        const uint4 a0 = *(const uint4*)&A[(size_t)(m0 + row_s) * DMODEL + k0 + cq];
        const uint4 a1 = *(const uint4*)&A[(size_t)(m0 + 64 + row_s) * DMODEL + k0 + cq];
        const uint4 b0 = *(const uint4*)&B[(size_t)(c0 + row_s) * DMODEL + k0 + cq];
        const uint4 b1 = *(const uint4*)&B[(size_t)(c0 + 64 + row_s) * DMODEL + k0 + cq];
        __syncthreads();
        *(uint4*)&As[row_s * 40 + cq] = a0;
        *(uint4*)&As[(64 + row_s) * 40 + cq] = a1;
        *(uint4*)&Bs[row_s * 40 + cq] = b0;
        *(uint4*)&Bs[(64 + row_s) * 40 + cq] = b1;
        __syncthreads();
        bf16x8 af[4], bf[4];
        #pragma unroll
        for (int im = 0; im < 4; ++im)
            af[im] = *(const bf16x8*)&As[(wr * 64 + im * 16 + col) * 40 + quad * 8];
        #pragma unroll
        for (int jn = 0; jn < 4; ++jn)
            bf[jn] = *(const bf16x8*)&Bs[(wc * 64 + jn * 16 + col) * 40 + quad * 8];
        #pragma unroll
        for (int im = 0; im < 4; ++im)
            #pragma unroll
            for (int jn = 0; jn < 4; ++jn)
                acc[im][jn] = __builtin_amdgcn_mfma_f32_16x16x32_bf16(af[im], bf[jn], acc[im][jn], 0, 0, 0);
    }

    const int cb = c0 + wc * 64;
    const int s = cb / DMODEL;
    const int h = (cb % DMODEL) >> 6;
    const int b = m0 >> 10;
    const int bh = b * NH + h;
    const int n0 = (m0 & (NSEQ - 1)) + wr * 64;
    const float qsc = 0.125f * LOG2E;

    #pragma unroll
    for (int im = 0; im < 4; ++im) {
        #pragma unroll
        for (int jn = 0; jn < 4; ++jn) {
            const int d = jn * 16 + col;
            const float bv = bias[cb + d];
            const f32x4 a = acc[im][jn];
            if (s == 0) {
                #pragma unroll
                for (int r = 0; r < 4; ++r) {
                    const int n = n0 + im * 16 + quad * 4 + r;
                    Qb[((size_t)bh * NSEQ + n) * HD + d] = f2bf((a[r] + bv) * qsc);
                }
            } else if (s == 1) {
                #pragma unroll
                for (int r = 0; r < 4; ++r) {
                    const int n = n0 + im * 16 + quad * 4 + r;
                    Kb[((size_t)bh * NSEQ + n) * HD + d] = f2bf(a[r] + bv);
                }
            } else {
                uint2 p;
                p.x = pk2(a[0] + bv, a[1] + bv);
                p.y = pk2(a[2] + bv, a[3] + bv);
                *(uint2*)&Vtb[((size_t)bh * HD + d) * NSEQ + n0 + im * 16 + quad * 4] = p;
            }
        }
    }
}

// ---------------------------------------------------------------------------
// Fused flash attention: K/V LDS double-buffered with register prefetch,
// ONE barrier per j-tile. P round-trips wave-private LDS rows (no barrier).
// exp2 domain; deferred l reduction.
// Staging: 256 thr × 2 uint4 each = 64x64 bf16 tile (rows srow, srow+32).
// ---------------------------------------------------------------------------
__global__ __launch_bounds__(256) void attn_mfma(
    const ushort_t* __restrict__ Qb, const ushort_t* __restrict__ Kb,
    const ushort_t* __restrict__ Vtb,
    const unsigned* __restrict__ pack,
    const float* __restrict__ table,
    ushort_t* __restrict__ Ob)
{
    __shared__ __align__(16) ushort_t Ks[2][64 * 72];
    __shared__ __align__(16) ushort_t Vt[2][64 * 72];
    __shared__ __align__(16) ushort_t Ps[64 * 72];
    __shared__ float tab[1024];
    __shared__ float red[4];

    const int t = threadIdx.x;
    const int lane = t & 63, w = t >> 6;
    const int col = lane & 15, quad = lane >> 4;
    const int bid = blockIdx.x;
    const int it = bid & 15, bh = bid >> 4;
    const int h = bh % NH, b = bh / NH;
    const int i0 = it * 64;

    // per-head table column (log2e-scaled) + block max
    float lm = -1e30f;
    for (int i = t; i < 1024; i += 256) {
        const float v = table[i * NH + h] * LOG2E;
        tab[i] = v;
        lm = fmaxf(lm, v);
    }
    #pragma unroll
    for (int off = 1; off < 64; off <<= 1)
        lm = fmaxf(lm, __shfl_xor(lm, off));
    if (lane == 0) red[w] = lm;

    // Q fragments direct from global (wave-private rows)
    const ushort_t* Qg = Qb + ((size_t)bh * NSEQ + i0 + w * 16 + col) * HD;
    const bf16x8 aq0 = *(const bf16x8*)(Qg + quad * 8);
    const bf16x8 aq1 = *(const bf16x8*)(Qg + 32 + quad * 8);

    const size_t kvbase = (size_t)bh * NSEQ * HD;
    const int rowb = w * 16 + quad * 4;
    const unsigned* prow = pack + ((size_t)b << 20) + (size_t)(i0 + rowb) * NSEQ + col;

    // staging coords: thread covers rows srow and srow+32, cols sc8..sc8+7
    const int srow = t >> 3, sc8 = (t & 7) * 8;
    const int so0 = srow * 72 + sc8;
    const int so1 = (srow + 32) * 72 + sc8;

    // stage tile 0 into buf0; prefetch tile 1 into regs
    uint4 k0 = *(const uint4*)&Kb[kvbase + (size_t)srow * HD + sc8];
    uint4 k1 = *(const uint4*)&Kb[kvbase + (size_t)(srow + 32) * HD + sc8];
    uint4 v0 = *(const uint4*)&Vtb[kvbase + (size_t)srow * NSEQ + sc8];
    uint4 v1 = *(const uint4*)&Vtb[kvbase + (size_t)(srow + 32) * NSEQ + sc8];
    *(uint4*)&Ks[0][so0] = k0;
    *(uint4*)&Ks[0][so1] = k1;
    *(uint4*)&Vt[0][so0] = v0;
    *(uint4*)&Vt[0][so1] = v1;
    k0 = *(const uint4*)&Kb[kvbase + (size_t)(64 + srow) * HD + sc8];
    k1 = *(const uint4*)&Kb[kvbase + (size_t)(64 + srow + 32) * HD + sc8];
    v0 = *(const uint4*)&Vtb[kvbase + (size_t)srow * NSEQ + 64 + sc8];
    v1 = *(const uint4*)&Vtb[kvbase + (size_t)(srow + 32) * NSEQ + 64 + sc8];

    unsigned pkr[16], pknew[16];
    #pragma unroll
    for (int r = 0; r < 4; ++r)
        #pragma unroll
        for (int jb = 0; jb < 4; ++jb)
            pkr[r * 4 + jb] = prow[(size_t)r * NSEQ + jb * 16];

    const f32x4 zero = {0.f, 0.f, 0.f, 0.f};
    f32x4 o_acc[4];
    #pragma unroll
    for (int i = 0; i < 4; ++i) o_acc[i] = zero;
    float m_r[4] = {-1e30f, -1e30f, -1e30f, -1e30f};
    float l_r[4] = {0.f, 0.f, 0.f, 0.f};
    float maxrb = 0.f;

    #pragma unroll 2
    for (int jt = 0; jt < 16; ++jt) {
        __syncthreads();   // the ONE barrier: prev readers done, staging visible
        if (jt == 0) maxrb = fmaxf(fmaxf(red[0], red[1]), fmaxf(red[2], red[3]));
        const int cur = jt & 1;

        // write prefetched tile jt+1 into the other buffer
        if (jt < 15) {
            *(uint4*)&Ks[cur ^ 1][so0] = k0;
            *(uint4*)&Ks[cur ^ 1][so1] = k1;
            *(uint4*)&Vt[cur ^ 1][so0] = v0;
            *(uint4*)&Vt[cur ^ 1][so1] = v1;
        }
        // issue global prefetch for tile jt+2
        if (jt < 14) {
            const int j2 = (jt + 2) * 64;
            k0 = *(const uint4*)&Kb[kvbase + (size_t)(j2 + srow) * HD + sc8];
            k1 = *(const uint4*)&Kb[kvbase + (size_t)(j2 + srow + 32) * HD + sc8];
            v0 = *(const uint4*)&Vtb[kvbase + (size_t)srow * NSEQ + j2 + sc8];
            v1 = *(const uint4*)&Vtb[kvbase + (size_t)(srow + 32) * NSEQ + j2 + sc8];
        }
        // issue pk prefetch for tile jt+1
        if (jt < 15) {
            const int j1 = (jt + 1) * 64;
            #pragma unroll
            for (int r = 0; r < 4; ++r)
                #pragma unroll
                for (int jb = 0; jb < 4; ++jb)
                    pknew[r * 4 + jb] = prow[(size_t)r * NSEQ + j1 + jb * 16];
        }

        // S = Q K^T  from Ks[cur]
        f32x4 sacc[4];
        #pragma unroll
        for (int jb = 0; jb < 4; ++jb) {
            sacc[jb] = zero;
            const bf16x8 b0 = *(const bf16x8*)&Ks[cur][(jb * 16 + col) * 72 + quad * 8];
            const bf16x8 b1 = *(const bf16x8*)&Ks[cur][(jb * 16 + col) * 72 + 32 + quad * 8];
            sacc[jb] = __builtin_amdgcn_mfma_f32_16x16x32_bf16(aq0, b0, sacc[jb], 0, 0, 0);
            sacc[jb] = __builtin_amdgcn_mfma_f32_16x16x32_bf16(aq1, b1, sacc[jb], 0, 0, 0);
        }

        // online softmax (exp2); P -> wave-private LDS rows
        #pragma unroll
        for (int r = 0; r < 4; ++r) {
            const int ri = rowb + r;
            float rmax = fmaxf(fmaxf(sacc[0][r], sacc[1][r]),
                               fmaxf(sacc[2][r], sacc[3][r]));
            #pragma unroll
            for (int off = 1; off < 16; off <<= 1)
                rmax = fmaxf(rmax, __shfl_xor(rmax, off));
            const float m_new = fmaxf(m_r[r], rmax + maxrb);
            const float corr = exp2f(m_r[r] - m_new);
            m_r[r] = m_new;
            float p[4];
            #pragma unroll
            for (int jb = 0; jb < 4; ++jb) {
                const unsigned pkv = pkr[r * 4 + jb];
                const float ebf = __uint_as_float(pkv & 0xFFFF0000u);
                const float rb = tab[pkv & 1023u];
                p[jb] = exp2f(sacc[jb][r] + rb + ebf - m_new);
            }
            l_r[r] = l_r[r] * corr + ((p[0] + p[1]) + (p[2] + p[3]));
            const unsigned u01 = pk2(p[0], p[1]);
            const unsigned u23 = pk2(p[2], p[3]);
            Ps[ri * 72 + col]      = (ushort_t)u01;
            Ps[ri * 72 + 16 + col] = (ushort_t)(u01 >> 16);
            Ps[ri * 72 + 32 + col] = (ushort_t)u23;
            Ps[ri * 72 + 48 + col] = (ushort_t)(u23 >> 16);
            #pragma unroll
            for (int db = 0; db < 4; ++db) o_acc[db][r] *= corr;
        }

        // O += P V  (wave-private P rows; same-wave DS in-order, no barrier)
        const bf16x8 ap0 = *(const bf16x8*)&Ps[(w * 16 + col) * 72 + quad * 8];
        const bf16x8 ap1 = *(const bf16x8*)&Ps[(w * 16 + col) * 72 + 32 + quad * 8];
        #pragma unroll
        for (int db = 0; db < 4; ++db) {
            const bf16x8 vv0 = *(const bf16x8*)&Vt[cur][(db * 16 + col) * 72 + quad * 8];
            const bf16x8 vv1 = *(const bf16x8*)&Vt[cur][(db * 16 + col) * 72 + 32 + quad * 8];
            o_acc[db] = __builtin_amdgcn_mfma_f32_16x16x32_bf16(ap0, vv0, o_acc[db], 0, 0, 0);
            o_acc[db] = __builtin_amdgcn_mfma_f32_16x16x32_bf16(ap1, vv1, o_acc[db], 0, 0, 0);
        }

        // rotate pk buffers
        if (jt < 15) {
            #pragma unroll
            for (int q = 0; q < 16; ++q) pkr[q] = pknew[q];
        }
    }

    // epilogue: finish deferred l reduction, normalize, store bf16
    #pragma unroll
    for (int r = 0; r < 4; ++r) {
        float l = l_r[r];
        #pragma unroll
        for (int off = 1; off < 16; off <<= 1)
            l += __shfl_xor(l, off);
        const float inv = 1.f / l;
        const int ri = rowb + r;
        const size_t base = ((size_t)(b * NSEQ) + i0 + ri) * DMODEL + h * HD;
        #pragma unroll
        for (int db = 0; db < 4; ++db)
            Ob[base + db * 16 + col] = f2bf(o_acc[db][r] * inv);
    }
}

// ---------------------------------------------------------------------------
// Proj GEMM (bf16 MFMA): 64x64 tiles for occupancy (768 blocks = 3/CU).
// 4 waves in 2x2; each wave 32x32 (2x2 accs). fp32 out.
// ---------------------------------------------------------------------------
__global__ __launch_bounds__(256) void proj_gemm(
    const ushort_t* __restrict__ A, const ushort_t* __restrict__ B,
    const float* __restrict__ bias, float* __restrict__ out)
{
    __shared__ __align__(16) ushort_t As[64 * 40];
    __shared__ __align__(16) ushort_t Bs[64 * 40];
    const int t = threadIdx.x;
    const int lane = t & 63, w = t >> 6;
    const int wr = w >> 1, wc = w & 1;
    const int col = lane & 15, quad = lane >> 4;
    const int m0 = blockIdx.y * 64, c0 = blockIdx.x * 64;

    const f32x4 zero = {0.f, 0.f, 0.f, 0.f};
    f32x4 acc[2][2];
    #pragma unroll
    for (int i = 0; i < 2; ++i)
        #pragma unroll
        for (int j = 0; j < 2; ++j) acc[i][j] = zero;

    const int srow = t >> 2, sc8 = (t & 3) * 8;
    for (int k0 = 0; k0 < DMODEL; k0 += 32) {
        const uint4 a0 = *(const uint4*)&A[(size_t)(m0 + srow) * DMODEL + k0 + sc8];
        const uint4 b0 = *(const uint4*)&B[(size_t)(c0 + srow) * DMODEL + k0 + sc8];
        __syncthreads();
        *(uint4*)&As[srow * 40 + sc8] = a0;
        *(uint4*)&Bs[srow * 40 + sc8] = b0;
        __syncthreads();
        bf16x8 af[2], bf[2];
        #pragma unroll
        for (int im = 0; im < 2; ++im)
            af[im] = *(const bf16x8*)&As[(wr * 32 + im * 16 + col) * 40 + quad * 8];
        #pragma unroll
        for (int jn = 0; jn < 2; ++jn)
            bf[jn] = *(const bf16x8*)&Bs[(wc * 32 + jn * 16 + col) * 40 + quad * 8];
        #pragma unroll
        for (int im = 0; im < 2; ++im)
            #pragma unroll
            for (int jn = 0; jn < 2; ++jn)
                acc[im][jn] = __builtin_amdgcn_mfma_f32_16x16x32_bf16(af[im], bf[jn], acc[im][jn], 0, 0, 0);
    }

    #pragma unroll
    for (int im = 0; im < 2; ++im) {
        #pragma unroll
        for (int jn = 0; jn < 2; ++jn) {
            const int c = c0 + wc * 32 + jn * 16 + col;
            const float bv = bias[c];
            #pragma unroll
            for (int r = 0; r < 4; ++r) {
                const int m = m0 + wr * 32 + im * 16 + quad * 4 + r;
                out[(size_t)m * DMODEL + c] = acc[im][jn][r] + bv;
            }
        }
    }
}

extern "C" void kernel_launch(void* const* d_in, const int* in_sizes, int n_in,
                              void* d_out, int out_size, void* d_ws, size_t ws_size,
                              hipStream_t stream) {
    const float* x       = (const float*)d_in[0];
    const float* coords  = (const float*)d_in[1];
    const float* elev    = (const float*)d_in[2];
    const float* qkv_w   = (const float*)d_in[3];
    const float* qkv_b   = (const float*)d_in[4];
    const float* proj_w  = (const float*)d_in[5];
    const float* proj_b  = (const float*)d_in[6];
    const float* btable  = (const float*)d_in[7];
    const float* alpha   = (const float*)d_in[8];
    float* out = (float*)d_out;

    ushort_t* wsu = (ushort_t*)d_ws;
    ushort_t* xb  = wsu;
    ushort_t* wqb = wsu + 3145728;
    ushort_t* pwb = wsu + 4915200;
    ushort_t* Qb  = wsu + 5505024;
    ushort_t* Kb  = wsu + 8650752;
    ushort_t* Vtb = wsu + 11796480;
    ushort_t* Ob  = wsu + 14942208;
    unsigned* pck = (unsigned*)(wsu + 18087936);   // 4M uint32 = 16 MB

    convert_kernel<<<2688, 256, 0, stream>>>(x, qkv_w, proj_w, wsu);
    bias_pre<<<4096, 256, 0, stream>>>(coords, elev, alpha, pck);
    qkv_gemm<<<dim3(18, 32), 256, 0, stream>>>(xb, wqb, qkv_b, Qb, Kb, Vtb);
    attn_mfma<<<768, 256, 0, stream>>>(Qb, Kb, Vtb, pck, btable, Ob);
    proj_gemm<<<dim3(12, 64), 256, 0, stream>>>(Ob, pwb, proj_b, out);
}

// Round 7
// 194.175 us; speedup vs baseline: 1.3912x; 1.0659x over previous
//
#include <hip/hip_runtime.h>
#include <hip/hip_bf16.h>
#include <math.h>

#define NH 12
#define HD 64
#define NSEQ 1024
#define DMODEL 768
#define LOG2E 1.44269504f

typedef unsigned short ushort_t;
typedef float f32x4 __attribute__((ext_vector_type(4)));
typedef short bf16x8 __attribute__((ext_vector_type(8)));

__device__ __forceinline__ ushort_t f2bf(float f) {
    unsigned int u = __float_as_uint(f);
    u += 0x7FFFu + ((u >> 16) & 1u);   // RNE
    return (ushort_t)(u >> 16);
}

__device__ __forceinline__ unsigned pk2(float x, float y) {
    __hip_bfloat162 t = __float22bfloat162_rn(make_float2(x, y));
    union { __hip_bfloat162 b; unsigned u; } c; c.b = t;
    return c.u;
}

// ---------------------------------------------------------------------------
// prep kernel: blocks [0,2688) convert x/qkv_w/proj_w fp32->bf16;
// blocks [2688, 6784) compute packed bias (bf16(elev*log2e)<<16 | bucket).
// ---------------------------------------------------------------------------
#define XB_N   3145728u
#define WQB_N  1769472u
#define PWB_N  589824u
#define CVT_BLOCKS 2688

__device__ __forceinline__ int bucketf(int rel) {
    const int n = -rel;
    const int u = (n < 0) ? 16 : 0;
    const int a = n < 0 ? -n : n;
    if (a < 8) return u + a;
    int v = 8 + (int)(log2f((float)a * 0.125f) * 2.0f + 1e-4f);
    if (v > 15) v = 15;
    return u + v;
}

__global__ __launch_bounds__(256) void prep_kernel(
    const float* __restrict__ x, const float* __restrict__ w1,
    const float* __restrict__ w2, ushort_t* __restrict__ dst,
    const float* __restrict__ coords, const float* __restrict__ elev,
    const float* __restrict__ alpha_p, unsigned* __restrict__ pack)
{
    const int t = threadIdx.x;
    if (blockIdx.x < CVT_BLOCKS) {
        const unsigned i = blockIdx.x * 256 + t;      // 8-elem chunk id
        const unsigned n0 = XB_N / 8, n1 = n0 + WQB_N / 8, n2 = n1 + PWB_N / 8;
        if (i >= n2) return;
        const float* src; unsigned off;
        if (i < n0)      { src = x;  off = i; }
        else if (i < n1) { src = w1; off = i - n0; }
        else             { src = w2; off = i - n1; }
        const float4 a = ((const float4*)src)[off * 2];
        const float4 b = ((const float4*)src)[off * 2 + 1];
        uint4 pk;
        pk.x = pk2(a.x, a.y); pk.y = pk2(a.z, a.w);
        pk.z = pk2(b.x, b.y); pk.w = pk2(b.z, b.w);
        ((uint4*)dst)[i] = pk;
    } else {
        const int blk = blockIdx.x - CVT_BLOCKS;
        const int b = blk >> 10, i = blk & 1023;
        const float alpha = alpha_p[0];
        const float2 ci = *(const float2*)&coords[(size_t)(b * NSEQ + i) * 2];
        const int cxi = (int)(ci.x * 128.0f), cyi = (int)(ci.y * 128.0f);
        const float ei = elev[b * NSEQ + i];
        const int j0 = t * 4;
        const float4 c01 = *(const float4*)&coords[(size_t)(b * NSEQ + j0) * 2];
        const float4 c23 = *(const float4*)&coords[(size_t)(b * NSEQ + j0 + 2) * 2];
        const float4 ej4 = *(const float4*)&elev[b * NSEQ + j0];
        const float cjx[4] = {c01.x, c01.z, c23.x, c23.z};
        const float cjy[4] = {c01.y, c01.w, c23.y, c23.w};
        const float ejv[4] = {ej4.x, ej4.y, ej4.z, ej4.w};
        unsigned r[4];
        #pragma unroll
        for (int k = 0; k < 4; ++k) {
            const int bx = bucketf(cxi - (int)(cjx[k] * 128.0f));
            const int by = bucketf(cyi - (int)(cjy[k] * 128.0f));
            const int idx = (bx << 5) + by;
            const float ed = (ejv[k] - ei) * 1e-3f;
            const float eb = fmaxf(-alpha * fmaxf(ed, 0.0f), -10.0f) * LOG2E;
            r[k] = ((unsigned)f2bf(eb) << 16) | (unsigned)idx;
        }
        uint4 o; o.x = r[0]; o.y = r[1]; o.z = r[2]; o.w = r[3];
        *(uint4*)&pack[((size_t)b << 20) + (size_t)i * NSEQ + j0] = o;
    }
}

// ---------------------------------------------------------------------------
// QKV GEMM (bf16 MFMA): 128x128 tile, 256 thr, BK=32.
// Q pre-scaled by 0.125*log2e; V transposed [bh][d][n].
// ---------------------------------------------------------------------------
__global__ __launch_bounds__(256) void qkv_gemm(
    const ushort_t* __restrict__ A, const ushort_t* __restrict__ B,
    const float* __restrict__ bias,
    ushort_t* __restrict__ Qb, ushort_t* __restrict__ Kb, ushort_t* __restrict__ Vtb)
{
    __shared__ __align__(16) ushort_t As[128 * 40];
    __shared__ __align__(16) ushort_t Bs[128 * 40];
    const int t = threadIdx.x;
    const int lane = t & 63, w = t >> 6;
    const int wr = w >> 1, wc = w & 1;
    const int col = lane & 15, quad = lane >> 4;
    const int m0 = blockIdx.y * 128, c0 = blockIdx.x * 128;

    const f32x4 zero = {0.f, 0.f, 0.f, 0.f};
    f32x4 acc[4][4];
    #pragma unroll
    for (int i = 0; i < 4; ++i)
        #pragma unroll
        for (int j = 0; j < 4; ++j) acc[i][j] = zero;

    const int row_s = t >> 2, cq = (t & 3) * 8;
    for (int k0 = 0; k0 < DMODEL; k0 += 32) {
        const uint4 a0 = *(const uint4*)&A[(size_t)(m0 + row_s) * DMODEL + k0 + cq];
        const uint4 a1 = *(const uint4*)&A[(size_t)(m0 + 64 + row_s) * DMODEL + k0 + cq];
        const uint4 b0 = *(const uint4*)&B[(size_t)(c0 + row_s) * DMODEL + k0 + cq];
        const uint4 b1 = *(const uint4*)&B[(size_t)(c0 + 64 + row_s) * DMODEL + k0 + cq];
        __syncthreads();
        *(uint4*)&As[row_s * 40 + cq] = a0;
        *(uint4*)&As[(64 + row_s) * 40 + cq] = a1;
        *(uint4*)&Bs[row_s * 40 + cq] = b0;
        *(uint4*)&Bs[(64 + row_s) * 40 + cq] = b1;
        __syncthreads();
        bf16x8 af[4], bf[4];
        #pragma unroll
        for (int im = 0; im < 4; ++im)
            af[im] = *(const bf16x8*)&As[(wr * 64 + im * 16 + col) * 40 + quad * 8];
        #pragma unroll
        for (int jn = 0; jn < 4; ++jn)
            bf[jn] = *(const bf16x8*)&Bs[(wc * 64 + jn * 16 + col) * 40 + quad * 8];
        #pragma unroll
        for (int im = 0; im < 4; ++im)
            #pragma unroll
            for (int jn = 0; jn < 4; ++jn)
                acc[im][jn] = __builtin_amdgcn_mfma_f32_16x16x32_bf16(af[im], bf[jn], acc[im][jn], 0, 0, 0);
    }

    const int cb = c0 + wc * 64;
    const int s = cb / DMODEL;
    const int h = (cb % DMODEL) >> 6;
    const int b = m0 >> 10;
    const int bh = b * NH + h;
    const int n0 = (m0 & (NSEQ - 1)) + wr * 64;
    const float qsc = 0.125f * LOG2E;

    #pragma unroll
    for (int im = 0; im < 4; ++im) {
        #pragma unroll
        for (int jn = 0; jn < 4; ++jn) {
            const int d = jn * 16 + col;
            const float bv = bias[cb + d];
            const f32x4 a = acc[im][jn];
            if (s == 0) {
                #pragma unroll
                for (int r = 0; r < 4; ++r) {
                    const int n = n0 + im * 16 + quad * 4 + r;
                    Qb[((size_t)bh * NSEQ + n) * HD + d] = f2bf((a[r] + bv) * qsc);
                }
            } else if (s == 1) {
                #pragma unroll
                for (int r = 0; r < 4; ++r) {
                    const int n = n0 + im * 16 + quad * 4 + r;
                    Kb[((size_t)bh * NSEQ + n) * HD + d] = f2bf(a[r] + bv);
                }
            } else {
                uint2 p;
                p.x = pk2(a[0] + bv, a[1] + bv);
                p.y = pk2(a[2] + bv, a[3] + bv);
                *(uint2*)&Vtb[((size_t)bh * HD + d) * NSEQ + n0 + im * 16 + quad * 4] = p;
            }
        }
    }
}

// ---------------------------------------------------------------------------
// Fused flash attention. S^T = K Q^T (swapped MFMA operands) so each lane's
// softmax values are j-adjacent: uint4 pk loads, uint2 P stores (2-way banks),
// 2-shfl row-max, one m/corr per lane. K/V LDS double-buffered, ONE barrier
// per j-tile; P round-trips wave-private LDS rows (no barrier).
// ---------------------------------------------------------------------------
__global__ __launch_bounds__(256) void attn_mfma(
    const ushort_t* __restrict__ Qb, const ushort_t* __restrict__ Kb,
    const ushort_t* __restrict__ Vtb,
    const unsigned* __restrict__ pack,
    const float* __restrict__ table,
    ushort_t* __restrict__ Ob)
{
    __shared__ __align__(16) ushort_t Ks[2][64 * 72];
    __shared__ __align__(16) ushort_t Vt[2][64 * 72];
    __shared__ __align__(16) ushort_t Ps[64 * 72];
    __shared__ float tab[1024];
    __shared__ float red[4];

    const int t = threadIdx.x;
    const int lane = t & 63, w = t >> 6;
    const int col = lane & 15, quad = lane >> 4;
    const int bid = blockIdx.x;
    const int it = bid & 15, bh = bid >> 4;
    const int h = bh % NH, b = bh / NH;
    const int i0 = it * 64;

    // per-head table column (log2e-scaled) + block max
    float lm = -1e30f;
    for (int i = t; i < 1024; i += 256) {
        const float v = table[i * NH + h] * LOG2E;
        tab[i] = v;
        lm = fmaxf(lm, v);
    }
    #pragma unroll
    for (int off = 1; off < 64; off <<= 1)
        lm = fmaxf(lm, __shfl_xor(lm, off));
    if (lane == 0) red[w] = lm;

    // Q fragments direct from global (wave-private rows i0+w*16+col)
    const ushort_t* Qg = Qb + ((size_t)bh * NSEQ + i0 + w * 16 + col) * HD;
    const bf16x8 aq0 = *(const bf16x8*)(Qg + quad * 8);
    const bf16x8 aq1 = *(const bf16x8*)(Qg + 32 + quad * 8);

    const size_t kvbase = (size_t)bh * NSEQ * HD;
    // pk row for this lane's Q-row (i = w*16+col), j base quad*4
    const unsigned* prow = pack + ((size_t)b << 20)
                         + (size_t)(i0 + w * 16 + col) * NSEQ + quad * 4;

    // staging coords: thread covers rows srow and srow+32, cols sc8..sc8+7
    const int srow = t >> 3, sc8 = (t & 7) * 8;
    const int so0 = srow * 72 + sc8;
    const int so1 = (srow + 32) * 72 + sc8;

    // stage tile 0 into buf0; prefetch tile 1 into regs
    uint4 k0 = *(const uint4*)&Kb[kvbase + (size_t)srow * HD + sc8];
    uint4 k1 = *(const uint4*)&Kb[kvbase + (size_t)(srow + 32) * HD + sc8];
    uint4 v0 = *(const uint4*)&Vtb[kvbase + (size_t)srow * NSEQ + sc8];
    uint4 v1 = *(const uint4*)&Vtb[kvbase + (size_t)(srow + 32) * NSEQ + sc8];
    *(uint4*)&Ks[0][so0] = k0;
    *(uint4*)&Ks[0][so1] = k1;
    *(uint4*)&Vt[0][so0] = v0;
    *(uint4*)&Vt[0][so1] = v1;
    k0 = *(const uint4*)&Kb[kvbase + (size_t)(64 + srow) * HD + sc8];
    k1 = *(const uint4*)&Kb[kvbase + (size_t)(64 + srow + 32) * HD + sc8];
    v0 = *(const uint4*)&Vtb[kvbase + (size_t)srow * NSEQ + 64 + sc8];
    v1 = *(const uint4*)&Vtb[kvbase + (size_t)(srow + 32) * NSEQ + 64 + sc8];

    const f32x4 zero = {0.f, 0.f, 0.f, 0.f};
    f32x4 o_acc[4];
    #pragma unroll
    for (int i = 0; i < 4; ++i) o_acc[i] = zero;
    float m_l = -1e30f;   // per-lane softmax state, Q-row i = w*16+col
    float l_l = 0.f;
    float maxrb = 0.f;

    #pragma unroll 2
    for (int jt = 0; jt < 16; ++jt) {
        __syncthreads();   // the ONE barrier per tile
        if (jt == 0) maxrb = fmaxf(fmaxf(red[0], red[1]), fmaxf(red[2], red[3]));
        const int cur = jt & 1;
        const int j0 = jt * 64;

        // write prefetched tile jt+1 into the other buffer
        if (jt < 15) {
            *(uint4*)&Ks[cur ^ 1][so0] = k0;
            *(uint4*)&Ks[cur ^ 1][so1] = k1;
            *(uint4*)&Vt[cur ^ 1][so0] = v0;
            *(uint4*)&Vt[cur ^ 1][so1] = v1;
        }
        // global prefetch for tile jt+2
        if (jt < 14) {
            const int j2 = (jt + 2) * 64;
            k0 = *(const uint4*)&Kb[kvbase + (size_t)(j2 + srow) * HD + sc8];
            k1 = *(const uint4*)&Kb[kvbase + (size_t)(j2 + srow + 32) * HD + sc8];
            v0 = *(const uint4*)&Vtb[kvbase + (size_t)srow * NSEQ + j2 + sc8];
            v1 = *(const uint4*)&Vtb[kvbase + (size_t)(srow + 32) * NSEQ + j2 + sc8];
        }
        // pk loads for THIS tile (latency covered by S-MFMA block below)
        uint4 pk4[4];
        #pragma unroll
        for (int jb = 0; jb < 4; ++jb)
            pk4[jb] = *(const uint4*)(prow + j0 + jb * 16);

        // S^T = K Q^T : per lane col=i, rows quad*4+r = j within jb block
        f32x4 sacc[4];
        #pragma unroll
        for (int jb = 0; jb < 4; ++jb) {
            sacc[jb] = zero;
            const bf16x8 kb0 = *(const bf16x8*)&Ks[cur][(jb * 16 + col) * 72 + quad * 8];
            const bf16x8 kb1 = *(const bf16x8*)&Ks[cur][(jb * 16 + col) * 72 + 32 + quad * 8];
            sacc[jb] = __builtin_amdgcn_mfma_f32_16x16x32_bf16(kb0, aq0, sacc[jb], 0, 0, 0);
            sacc[jb] = __builtin_amdgcn_mfma_f32_16x16x32_bf16(kb1, aq1, sacc[jb], 0, 0, 0);
        }

        // per-lane online softmax over 16 j-values (all same Q-row i)
        float mx = fmaxf(fmaxf(fmaxf(sacc[0][0], sacc[0][1]), fmaxf(sacc[0][2], sacc[0][3])),
                         fmaxf(fmaxf(sacc[1][0], sacc[1][1]), fmaxf(sacc[1][2], sacc[1][3])));
        mx = fmaxf(mx, fmaxf(fmaxf(fmaxf(sacc[2][0], sacc[2][1]), fmaxf(sacc[2][2], sacc[2][3])),
                             fmaxf(fmaxf(sacc[3][0], sacc[3][1]), fmaxf(sacc[3][2], sacc[3][3]))));
        mx = fmaxf(mx, __shfl_xor(mx, 16));
        mx = fmaxf(mx, __shfl_xor(mx, 32));
        const float m_new = fmaxf(m_l, mx + maxrb);
        const float corr = exp2f(m_l - m_new);
        m_l = m_new;

        float psum = 0.f;
        #pragma unroll
        for (int jb = 0; jb < 4; ++jb) {
            const uint4 pkv = pk4[jb];
            const float p0 = exp2f(sacc[jb][0] + tab[pkv.x & 1023u] + __uint_as_float(pkv.x & 0xFFFF0000u) - m_new);
            const float p1 = exp2f(sacc[jb][1] + tab[pkv.y & 1023u] + __uint_as_float(pkv.y & 0xFFFF0000u) - m_new);
            const float p2 = exp2f(sacc[jb][2] + tab[pkv.z & 1023u] + __uint_as_float(pkv.z & 0xFFFF0000u) - m_new);
            const float p3 = exp2f(sacc[jb][3] + tab[pkv.w & 1023u] + __uint_as_float(pkv.w & 0xFFFF0000u) - m_new);
            psum += (p0 + p1) + (p2 + p3);
            uint2 st;
            st.x = pk2(p0, p1);
            st.y = pk2(p2, p3);
            *(uint2*)&Ps[(w * 16 + col) * 72 + jb * 16 + quad * 4] = st;
        }
        l_l = l_l * corr + psum;

        // broadcast corr to o_acc's row layout (rows i = quad*4+r)
        float corr_r[4];
        #pragma unroll
        for (int r = 0; r < 4; ++r)
            corr_r[r] = __shfl(corr, w * 16 + quad * 4 + r);
        #pragma unroll
        for (int db = 0; db < 4; ++db) {
            o_acc[db][0] *= corr_r[0]; o_acc[db][1] *= corr_r[1];
            o_acc[db][2] *= corr_r[2]; o_acc[db][3] *= corr_r[3];
        }

        // O += P V  (wave-private P rows; same-wave DS in-order, no barrier)
        const bf16x8 ap0 = *(const bf16x8*)&Ps[(w * 16 + col) * 72 + quad * 8];
        const bf16x8 ap1 = *(const bf16x8*)&Ps[(w * 16 + col) * 72 + 32 + quad * 8];
        #pragma unroll
        for (int db = 0; db < 4; ++db) {
            const bf16x8 vv0 = *(const bf16x8*)&Vt[cur][(db * 16 + col) * 72 + quad * 8];
            const bf16x8 vv1 = *(const bf16x8*)&Vt[cur][(db * 16 + col) * 72 + 32 + quad * 8];
            o_acc[db] = __builtin_amdgcn_mfma_f32_16x16x32_bf16(ap0, vv0, o_acc[db], 0, 0, 0);
            o_acc[db] = __builtin_amdgcn_mfma_f32_16x16x32_bf16(ap1, vv1, o_acc[db], 0, 0, 0);
        }
    }

    // epilogue: finish l reduction (over quad copies), normalize, store bf16
    float l = l_l;
    l += __shfl_xor(l, 16);
    l += __shfl_xor(l, 32);
    #pragma unroll
    for (int r = 0; r < 4; ++r) {
        const float lr = __shfl(l, w * 16 + quad * 4 + r);
        const float inv = 1.f / lr;
        const int ri = w * 16 + quad * 4 + r;
        const size_t base = ((size_t)(b * NSEQ) + i0 + ri) * DMODEL + h * HD;
        #pragma unroll
        for (int db = 0; db < 4; ++db)
            Ob[base + db * 16 + col] = f2bf(o_acc[db][r] * inv);
    }
}

// ---------------------------------------------------------------------------
// Proj GEMM (bf16 MFMA): 64x64 tiles (768 blocks = 3/CU). fp32 out.
// ---------------------------------------------------------------------------
__global__ __launch_bounds__(256) void proj_gemm(
    const ushort_t* __restrict__ A, const ushort_t* __restrict__ B,
    const float* __restrict__ bias, float* __restrict__ out)
{
    __shared__ __align__(16) ushort_t As[64 * 40];
    __shared__ __align__(16) ushort_t Bs[64 * 40];
    const int t = threadIdx.x;
    const int lane = t & 63, w = t >> 6;
    const int wr = w >> 1, wc = w & 1;
    const int col = lane & 15, quad = lane >> 4;
    const int m0 = blockIdx.y * 64, c0 = blockIdx.x * 64;

    const f32x4 zero = {0.f, 0.f, 0.f, 0.f};
    f32x4 acc[2][2];
    #pragma unroll
    for (int i = 0; i < 2; ++i)
        #pragma unroll
        for (int j = 0; j < 2; ++j) acc[i][j] = zero;

    const int srow = t >> 2, sc8 = (t & 3) * 8;
    for (int k0 = 0; k0 < DMODEL; k0 += 32) {
        const uint4 a0 = *(const uint4*)&A[(size_t)(m0 + srow) * DMODEL + k0 + sc8];
        const uint4 b0 = *(const uint4*)&B[(size_t)(c0 + srow) * DMODEL + k0 + sc8];
        __syncthreads();
        *(uint4*)&As[srow * 40 + sc8] = a0;
        *(uint4*)&Bs[srow * 40 + sc8] = b0;
        __syncthreads();
        bf16x8 af[2], bf[2];
        #pragma unroll
        for (int im = 0; im < 2; ++im)
            af[im] = *(const bf16x8*)&As[(wr * 32 + im * 16 + col) * 40 + quad * 8];
        #pragma unroll
        for (int jn = 0; jn < 2; ++jn)
            bf[jn] = *(const bf16x8*)&Bs[(wc * 32 + jn * 16 + col) * 40 + quad * 8];
        #pragma unroll
        for (int im = 0; im < 2; ++im)
            #pragma unroll
            for (int jn = 0; jn < 2; ++jn)
                acc[im][jn] = __builtin_amdgcn_mfma_f32_16x16x32_bf16(af[im], bf[jn], acc[im][jn], 0, 0, 0);
    }

    #pragma unroll
    for (int im = 0; im < 2; ++im) {
        #pragma unroll
        for (int jn = 0; jn < 2; ++jn) {
            const int c = c0 + wc * 32 + jn * 16 + col;
            const float bv = bias[c];
            #pragma unroll
            for (int r = 0; r < 4; ++r) {
                const int m = m0 + wr * 32 + im * 16 + quad * 4 + r;
                out[(size_t)m * DMODEL + c] = acc[im][jn][r] + bv;
            }
        }
    }
}

extern "C" void kernel_launch(void* const* d_in, const int* in_sizes, int n_in,
                              void* d_out, int out_size, void* d_ws, size_t ws_size,
                              hipStream_t stream) {
    const float* x       = (const float*)d_in[0];
    const float* coords  = (const float*)d_in[1];
    const float* elev    = (const float*)d_in[2];
    const float* qkv_w   = (const float*)d_in[3];
    const float* qkv_b   = (const float*)d_in[4];
    const float* proj_w  = (const float*)d_in[5];
    const float* proj_b  = (const float*)d_in[6];
    const float* btable  = (const float*)d_in[7];
    const float* alpha   = (const float*)d_in[8];
    float* out = (float*)d_out;

    ushort_t* wsu = (ushort_t*)d_ws;
    ushort_t* xb  = wsu;
    ushort_t* wqb = wsu + 3145728;
    ushort_t* pwb = wsu + 4915200;
    ushort_t* Qb  = wsu + 5505024;
    ushort_t* Kb  = wsu + 8650752;
    ushort_t* Vtb = wsu + 11796480;
    ushort_t* Ob  = wsu + 14942208;
    unsigned* pck = (unsigned*)(wsu + 18087936);   // 4M uint32 = 16 MB

    prep_kernel<<<CVT_BLOCKS + 4096, 256, 0, stream>>>(
        x, qkv_w, proj_w, wsu, coords, elev, alpha, pck);
    qkv_gemm<<<dim3(18, 32), 256, 0, stream>>>(xb, wqb, qkv_b, Qb, Kb, Vtb);
    attn_mfma<<<768, 256, 0, stream>>>(Qb, Kb, Vtb, pck, btable, Ob);
    proj_gemm<<<dim3(12, 64), 256, 0, stream>>>(Ob, pwb, proj_b, out);
}